// Round 4
// baseline (438.696 us; speedup 1.0000x reference)
//
#include <hip/hip_runtime.h>

// Input:  x[b][c][h][w], B=8, C=32, H=512, W=512 (fp32)
// Output: out[b][q][c][h2][w2], q in {LL,LH,HL,HH}, h2=H/2=256, w2=W/2=256 (fp32)
//
// 2-deep software-pipelined grid-stride loop:
//   iteration k: issue the 4 loads for tile k+1, THEN compute+store tile k.
//   The vmcnt wait for tile k's loads lands ~1 full iteration after issue, so
//   read latency is covered and loads get a head start on the write stream.
//   (Unpipelined versions plateaued at ~150-165us / 2.4 TB/s: every iteration
//   was load -> full drain -> store, so reads queued behind writes with zero
//   head start. VGPR=24 showed the compiler wasn't pipelining on its own.)

#define B_   8
#define C_   32
#define H2_  256
#define W2_  256
#define WQ_  (W2_/4)            // 64 float4-wide output groups per row

typedef float v4f __attribute__((ext_vector_type(4)));

__device__ __forceinline__ void haar4(const v4f& t0, const v4f& t1,
                                      const v4f& u0, const v4f& u1,
                                      v4f& LL, v4f& LH, v4f& HL, v4f& HH) {
    { float s0 = t0.x + t0.y, d0 = t0.x - t0.y;
      float s1 = u0.x + u0.y, d1 = u0.x - u0.y;
      LL.x = (s0 + s1) * 0.5f; LH.x = (s0 - s1) * 0.5f;
      HL.x = (d0 + d1) * 0.5f; HH.x = (d0 - d1) * 0.5f; }
    { float s0 = t0.z + t0.w, d0 = t0.z - t0.w;
      float s1 = u0.z + u0.w, d1 = u0.z - u0.w;
      LL.y = (s0 + s1) * 0.5f; LH.y = (s0 - s1) * 0.5f;
      HL.y = (d0 + d1) * 0.5f; HH.y = (d0 - d1) * 0.5f; }
    { float s0 = t1.x + t1.y, d0 = t1.x - t1.y;
      float s1 = u1.x + u1.y, d1 = u1.x - u1.y;
      LL.z = (s0 + s1) * 0.5f; LH.z = (s0 - s1) * 0.5f;
      HL.z = (d0 + d1) * 0.5f; HH.z = (d0 - d1) * 0.5f; }
    { float s0 = t1.z + t1.w, d0 = t1.z - t1.w;
      float s1 = u1.z + u1.w, d1 = u1.z - u1.w;
      LL.w = (s0 + s1) * 0.5f; LH.w = (s0 - s1) * 0.5f;
      HL.w = (d0 + d1) * 0.5f; HH.w = (d0 - d1) * 0.5f; }
}

__device__ __forceinline__ size_t read_base(int tid) {
    const int wq = tid & (WQ_ - 1);           // 0..63
    const int h2 = (tid >> 6) & (H2_ - 1);    // 0..255
    const int bc = tid >> 14;                 // b*32 + c, 0..255
    // rows 2*h2 and 2*h2+1 of image bc; row = 128 v4f
    return ((size_t)bc * 512 + 2 * h2) * 128 + 2 * wq;
}

__device__ __forceinline__ size_t write_base(int tid) {
    const int wq = tid & (WQ_ - 1);
    const int h2 = (tid >> 6) & (H2_ - 1);
    const int bc = tid >> 14;
    // out v4f index: ((b*4 + q)*C + c)*H2*W2/4 + h2*W2/4 + wq
    return ((size_t)(bc >> 5) * (4 * C_) + (bc & (C_ - 1))) * (H2_ * W2_ / 4)
         + (size_t)h2 * (W2_ / 4) + wq;
}

__global__ __launch_bounds__(256)
void WaveletTransform_14319420965150_kernel(const float* __restrict__ x,
                                            float* __restrict__ out) {
    const int stride = gridDim.x * blockDim.x;    // 524,288
    const v4f* __restrict__ xin = (const v4f*)x;
    v4f* __restrict__ o         = (v4f*)out;
    const size_t qstride = (size_t)C_ * (H2_ * W2_ / 4);  // 8 MiB in v4f units

    int tid = blockIdx.x * blockDim.x + threadIdx.x;

    // prologue: loads for tile 0
    size_t r = read_base(tid);
    v4f t0 = xin[r], t1 = xin[r + 1], u0 = xin[r + 128], u1 = xin[r + 129];

    #pragma unroll 1
    for (int k = 0; k < 7; ++k) {
        const int tnext = tid + stride;
        // issue next tile's loads FIRST (stay in flight across compute+stores)
        const size_t rn = read_base(tnext);
        v4f n0 = xin[rn], n1 = xin[rn + 1], n2 = xin[rn + 128], n3 = xin[rn + 129];

        v4f LL, LH, HL, HH;
        haar4(t0, t1, u0, u1, LL, LH, HL, HH);
        const size_t ob = write_base(tid);
        o[ob]               = LL;
        o[ob +     qstride] = LH;
        o[ob + 2 * qstride] = HL;
        o[ob + 3 * qstride] = HH;

        t0 = n0; t1 = n1; u0 = n2; u1 = n3;
        tid = tnext;
    }

    // epilogue: last tile
    v4f LL, LH, HL, HH;
    haar4(t0, t1, u0, u1, LL, LH, HL, HH);
    const size_t ob = write_base(tid);
    o[ob]               = LL;
    o[ob +     qstride] = LH;
    o[ob + 2 * qstride] = HL;
    o[ob + 3 * qstride] = HH;
}

extern "C" void kernel_launch(void* const* d_in, const int* in_sizes, int n_in,
                              void* d_out, int out_size, void* d_ws, size_t ws_size,
                              hipStream_t stream) {
    const float* x = (const float*)d_in[0];
    float* out = (float*)d_out;
    const int block = 256;
    const int grid  = 2048;   // 8 blocks/CU x 256 CUs; 8 tiles per thread
    WaveletTransform_14319420965150_kernel<<<grid, block, 0, stream>>>(x, out);
}

// Round 5
// 426.097 us; speedup vs baseline: 1.0296x; 1.0296x over previous
//
#include <hip/hip_runtime.h>

// Input:  x[b][c][h][w], B=8, C=32, H=512, W=512 (fp32)
// Output: out[b][q][c][h2][w2], q in {LL,LH,HL,HH}, h2=256, w2=256 (fp32)
//
// LDS-decoupled structure. Per block (256 thr): one (b,c) image, 8 output rows.
//  Load phase: 16 input rows; each thread 8 independent dwordx4 loads (batch-
//    issued, so no store ever precedes a load in the vmcnt stream), horizontal
//    sum/diff precomputed in registers, staged to LDS as s/d planes (32 KB).
//  Store phase: wave q emits ONLY quadrant q: 8 rows x 1 KB contiguous wave
//    stores (8 KB single-stream per wave), fed by contiguous ds_read_b128
//    (conflict-free canonical pattern). Kills the 4-stream 8MiB-stride
//    per-wave write scatter and the load/store vmcnt coupling that all four
//    previous ~150-165us variants shared.

#define C_ 32
typedef float v4f __attribute__((ext_vector_type(4)));

__global__ __launch_bounds__(256)
void WaveletTransform_14319420965150_kernel(const float* __restrict__ x,
                                            float* __restrict__ out) {
    // s/d planes for 16 input rows: [plane][row][64 v4f] = 32 KiB
    __shared__ v4f sd[2][16][64];

    const int bid = blockIdx.x;        // 0..8191
    const int bc  = bid >> 5;          // b*32+c, 0..255
    const int h2b = bid & 31;          // 8-output-row block within image

    const v4f* __restrict__ xin = (const v4f*)x;
    v4f* __restrict__ o         = (v4f*)out;

    const int t    = threadIdx.x;
    const int lane = t & 63;
    const int wid  = t >> 6;           // 0..3

    // ---------------- load phase ----------------
    // wave w loads input rows {4j+w}, lane k covers v4f pair (2k, 2k+1)
    // image = 65536 v4f, row = 128 v4f; tile starts at input row 16*h2b
    const size_t imgbase = (size_t)bc * 65536 + (size_t)h2b * (16 * 128);

    v4f a[4], b[4];
    #pragma unroll
    for (int j = 0; j < 4; ++j) {
        const size_t g = imgbase + (size_t)(4 * j + wid) * 128 + 2 * lane;
        a[j] = xin[g];
        b[j] = xin[g + 1];
    }
    #pragma unroll
    for (int j = 0; j < 4; ++j) {
        const int r = 4 * j + wid;
        v4f s = { a[j].x + a[j].y, a[j].z + a[j].w,
                  b[j].x + b[j].y, b[j].z + b[j].w };
        v4f d = { a[j].x - a[j].y, a[j].z - a[j].w,
                  b[j].x - b[j].y, b[j].z - b[j].w };
        sd[0][r][lane] = s;     // contiguous 1 KB wave write, conflict-free
        sd[1][r][lane] = d;
    }
    __syncthreads();

    // ---------------- store phase ----------------
    // wave q -> quadrant q: q=0 LL=(s_t+s_b)/2, 1 LH=(s_t-s_b)/2,
    //                       2 HL=(d_t+d_b)/2, 3 HH=(d_t-d_b)/2
    const int q = wid;
    const int p = q >> 1;              // 0: s-plane, 1: d-plane
    const bool neg = (q & 1);
    // out v4f index: ((b*4+q)*32 + c)*16384 + h2*64 + lane
    size_t ob = ((size_t)(bc >> 5) * 128 + (size_t)q * C_ + (bc & (C_ - 1))) * 16384
              + (size_t)(h2b * 8) * 64 + lane;

    #pragma unroll
    for (int r = 0; r < 8; ++r) {
        v4f top = sd[p][2 * r][lane];      // contiguous b128, conflict-free
        v4f bot = sd[p][2 * r + 1][lane];
        v4f res = neg ? (top - bot) * 0.5f : (top + bot) * 0.5f;
        o[ob + (size_t)r * 64] = res;      // contiguous 1 KB wave store
    }
}

extern "C" void kernel_launch(void* const* d_in, const int* in_sizes, int n_in,
                              void* d_out, int out_size, void* d_ws, size_t ws_size,
                              hipStream_t stream) {
    const float* x = (const float*)d_in[0];
    float* out = (float*)d_out;
    const int block = 256;
    const int grid  = 8192;   // 256 images x 32 row-blocks, one tile per block
    WaveletTransform_14319420965150_kernel<<<grid, block, 0, stream>>>(x, out);
}